// Round 14
// baseline (79.719 us; speedup 1.0000x reference)
//
#include <hip/hip_runtime.h>
#include <math.h>

#define N 4096
#define N5 (N * 5)
#define FEPS 1e-7f
#define HEPS 5e-8f      // FEPS/2, split across the two records of a pair
#define BLK 256
#define ROWS 2          // rows per thread: one 3xb128 broadcast feeds 4 pairs
#define JT 128          // j-chunks; grid = (4096/512)*128 = 1024 blocks = 4/CU
#define CH (N / JT)     // 32 j's per block
#define NPAIR (CH / 2)  // 16 packed j-pairs per block
#define KATAN 0.6366197723675814f   // 2/pi (folds 4/pi^2 into atan)
#define SQL2E 1.2011224087864498f   // sqrt(log2 e), folds exp->exp2 into conf
#define ISQL2E 0.8325546111576977f  // 1/SQL2E, unfolds cf2 in a0 (measured absmax 0)

typedef float v2f __attribute__((ext_vector_type(2)));

// d_ws: part[jt][c][i] : JT*6*N floats = 12.6 MB.
//
// r14 = r13 RESUBMITTED UNCHANGED. r13 died with "container failed twice"
// -- an infra-level error fired before any bench timing. The kernel has no
// hang mechanism (two plain dispatches, no cooperative launch, no atomics,
// no spin, no memset; indexing audited: i in [0,4096), LDS max idx 191/192,
// 12.6MB part = same footprint r3/r9 ran fine). A failed measurement is not
// a falsified theory -> retry.
//
// Theory under test (r9 probe + r10 partial-win established main kernel is
// LDS-PIPE-bound: per-CU shared pipe, 3xb128 = ~36cy per pair-iter):
// ROWS=2 @ JT=128 halves LDS cost PER PAIR at CONSTANT occupancy:
//   grid stays 1024 blocks = 4 blocks/CU = 16 waves/CU (the only geometry
//   ever measured good); each 3xb128 broadcast feeds 2j x 2rows = 4 pairs;
//   the 5 j-derived v2f ops are shared across rows.
// Models: LDS/CU 7.7 -> 3.8us, VALU/SIMD ~5.5us -> main ~8-10us (was ~13).
// (r3's ROWS=4 regression was at HALVED occupancy with the fat 12-field
// scalar loop -- different failure mode.)
// Epilogue: 128 slots, r10's proven 4-thr/output shape, 32 slots each.
// Prediction: 77.75 -> ~73-75us. Pre-committed: neutral -> declare
// convergence; >80 -> revert r10; infra-fail again -> revert r10 verbatim.
//
// Kept (measured through r10): packed-v2f one-rcp common-denominator CIoU:
//   P=(v+1+eps)*uni-inter (=den*uni, clamp>=1e-12; cancels in the ratio on
//   the diagonal), ciou=[P*(inter*c2-rho2*uni)-v^2*uni^2*c2]/(uni*c2*P);
// 6-field LDS record, derived fields in VALU, a0 cf2-folded + ISQL2E unfold,
// eps split across records, 4/pi^2 in atan, log2e in conf.
// NO 2nd __launch_bounds__ arg (measured: forcing waves/EU spills).

__device__ __forceinline__ v2f min2(v2f a, v2f b) {
    v2f r; r.x = fminf(a.x, b.x); r.y = fminf(a.y, b.y); return r;
}
__device__ __forceinline__ v2f max2(v2f a, v2f b) {
    v2f r; r.x = fmaxf(a.x, b.x); r.y = fmaxf(a.y, b.y); return r;
}
__device__ __forceinline__ v2f rcp2(v2f a) {
    v2f r; r.x = __builtin_amdgcn_rcpf(a.x); r.y = __builtin_amdgcn_rcpf(a.y); return r;
}
__device__ __forceinline__ v2f exp22(v2f a) {
    v2f r; r.x = __builtin_amdgcn_exp2f(a.x); r.y = __builtin_amdgcn_exp2f(a.y); return r;
}

// Packed-SoA pair records in LDS: pair p stride 12 floats (48 B, 16-aligned):
// [x1a,x1b, y1a,y1b, x2a,x2b, y2a,y2b, ata,atb, cf2a,cf2b]
__global__ __launch_bounds__(BLK) void ciou_attn_kernel(
        const float* __restrict__ x,
        float* __restrict__ part) {
    __shared__ float jrec[NPAIR * 12];   // 768 B
    const int tid = threadIdx.x;
    const int gb = blockIdx.x / JT;
    const int jt = blockIdx.x % JT;

    // Stage j-chunk in-kernel (first CH threads; one atanf each).
    if (tid < CH) {
        int j = jt * CH + tid;
        float cf = x[j * 5 + 0], jx1 = x[j * 5 + 1], jy1 = x[j * 5 + 2];
        float jx2 = x[j * 5 + 3], jy2 = x[j * 5 + 4];
        float* dp = &jrec[(tid >> 1) * 12 + (tid & 1)];
        dp[0]  = jx1;  dp[2] = jy1;  dp[4] = jx2;  dp[6] = jy2;
        dp[8]  = KATAN * atanf((jx2 - jx1) / ((jy2 - jy1) + FEPS));
        dp[10] = cf * SQL2E;
    }

    // Per-lane row records for 2 rows (stride BLK apart -> coalesced).
    float rx1[ROWS], ry1[ROWS], rx2[ROWS], ry2[ROWS], rw[ROWS], rh[ROWS];
    float rhx[ROWS], rhy[ROWS], rareps[ROWS], rat[ROWS], rcf2[ROWS];
#pragma unroll
    for (int r = 0; r < ROWS; r++) {
        const int i = gb * (BLK * ROWS) + r * BLK + tid;
        rx1[r] = x[i * 5 + 1]; ry1[r] = x[i * 5 + 2];
        rx2[r] = x[i * 5 + 3]; ry2[r] = x[i * 5 + 4];
        rw[r] = rx2[r] - rx1[r]; rh[r] = ry2[r] - ry1[r];
        rhx[r] = (rx1[r] + rx2[r]) * 0.5f; rhy[r] = (ry1[r] + ry2[r]) * 0.5f;
        rareps[r] = fmaf(rw[r], rh[r], HEPS);
        rat[r] = KATAN * atanf(rw[r] / (rh[r] + FEPS));
        rcf2[r] = x[i * 5 + 0] * SQL2E;
    }

    __syncthreads();

    v2f sum[ROWS], a0[ROWS], a1[ROWS], a2[ROWS], a3[ROWS], a4[ROWS];
#pragma unroll
    for (int r = 0; r < ROWS; r++) {
        sum[r] = 0.f; a0[r] = 0.f; a1[r] = 0.f;
        a2[r] = 0.f; a3[r] = 0.f; a4[r] = 0.f;
    }
    const float ONEP = 1.f + FEPS;

#pragma unroll 4
    for (int p = 0; p < NPAIR; p++) {
        const float* f = &jrec[p * 12];   // uniform addr -> 3x b128 broadcast
        const v2f X1 = *(const v2f*)(f + 0),  Y1 = *(const v2f*)(f + 2);
        const v2f X2 = *(const v2f*)(f + 4),  Y2 = *(const v2f*)(f + 6);
        const v2f AT = *(const v2f*)(f + 8),  CF2 = *(const v2f*)(f + 10);
        // Derived j-fields (shared across both rows).
        const v2f W = X2 - X1, H = Y2 - Y1;
        const v2f HX = (X1 + X2) * 0.5f, HY = (Y1 + Y2) * 0.5f;
        const v2f AR = W * H + HEPS;

#pragma unroll
        for (int r = 0; r < ROWS; r++) {
            v2f iwr = min2(rx2[r], X2) - max2(rx1[r], X1);
            v2f ihr = min2(ry2[r], Y2) - max2(ry1[r], Y1);
            v2f inter = max2(iwr, 0.f) * max2(ihr, 0.f);
            v2f uni = (rareps[r] + AR) - inter;
            v2f cw = (rw[r] + W) - iwr;          // enclosing box identity
            v2f chh = (rh[r] + H) - ihr;
            v2f c2 = cw * cw + chh * chh + FEPS;
            v2f dx = HX - rhx[r];
            v2f dy = HY - rhy[r];
            v2f rho2 = dx * dx + dy * dy;        // /4 pre-folded
            v2f da = AT - rat[r];                // 4/pi^2 pre-folded
            v2f v = da * da;
            v2f P = (v + ONEP) * uni - inter;    // den*uni
            P = max2(P, 1e-12f);                 // fp-cancellation guard
            v2f rr = rcp2(uni * c2 * P);         // one rcp per pair
            v2f t1 = inter * c2 - rho2 * uni;
            v2f vu = v * uni;
            v2f num = t1 * P - (vu * vu) * c2;
            v2f e = exp22((num * rr) * (rcf2[r] * CF2));
            sum[r] += e;
            a0[r] += e * CF2;                    // cf2-folded; unfold at store
            a1[r] += e * X1;
            a2[r] += e * Y1;
            a3[r] += e * X2;
            a4[r] += e * Y2;
        }
    }

    // Coalesced partial stores: [jt][c][i], lanes contiguous in i.
    float* pp = part + (size_t)jt * 6 * N;
#pragma unroll
    for (int r = 0; r < ROWS; r++) {
        const int i = gb * (BLK * ROWS) + r * BLK + tid;
        pp[0 * N + i] = sum[r].x + sum[r].y;
        pp[1 * N + i] = (a0[r].x + a0[r].y) * ISQL2E;
        pp[2 * N + i] = a1[r].x + a1[r].y;
        pp[3 * N + i] = a2[r].x + a2[r].y;
        pp[4 * N + i] = a3[r].x + a3[r].y;
        pp[5 * N + i] = a4[r].x + a4[r].y;
    }
}

// 4 threads per output element: thread (o=t&63, q=t>>6) sums jt-slots
// [q*32, q*32+32); LDS reduce across q; t<64 finishes. 320 blocks = 1280
// waves. All part loads coalesced (block's 64 outputs share c, i contiguous).
__global__ void epilogue_kernel(const float* __restrict__ x,
                                const float* __restrict__ gamma,
                                const float* __restrict__ part,
                                float* __restrict__ out) {
    __shared__ float red[2][BLK];
    const int t = threadIdx.x;
    const int o = t & 63, q = t >> 6;
    const int idx = blockIdx.x * 64 + o;
    const int c = idx / N, i = idx - c * N;
    float se = 0.f, a = 0.f;
    const float* ps = part + (size_t)(q * (JT / 4)) * 6 * N;
#pragma unroll 8
    for (int k = 0; k < JT / 4; k++) {
        const float* p = ps + (size_t)k * 6 * N;
        se += p[0 * N + i];
        a  += p[(1 + c) * N + i];
    }
    red[0][t] = se; red[1][t] = a;
    __syncthreads();
    if (t < 64) {
        float se4 = (red[0][t] + red[0][t + 64]) + (red[0][t + 128] + red[0][t + 192]);
        float a4  = (red[1][t] + red[1][t + 64]) + (red[1][t + 128] + red[1][t + 192]);
        float xp = x[i * 5 + c] * gamma[0] + a4 / se4;
        out[i * 5 + c] = 1.f / (1.f + expf(-xp));
    }
}

extern "C" void kernel_launch(void* const* d_in, const int* in_sizes, int n_in,
                              void* d_out, int out_size, void* d_ws, size_t ws_size,
                              hipStream_t stream) {
    const float* x = (const float*)d_in[0];
    const float* gamma = (const float*)d_in[1];
    float* out = (float*)d_out;
    float* part = (float*)d_ws;  // JT*6*N floats = 12.6 MB

    ciou_attn_kernel<<<(N / (BLK * ROWS)) * JT, BLK, 0, stream>>>(x, part);
    epilogue_kernel<<<N5 / 64, BLK, 0, stream>>>(x, gamma, part, out);
}

// Round 15
// 77.186 us; speedup vs baseline: 1.0328x; 1.0328x over previous
//
#include <hip/hip_runtime.h>
#include <math.h>

#define N 4096
#define FEPS 1e-7f
#define HEPS 5e-8f      // FEPS/2, split across the two records of a pair
#define BLK 256
#define JT 64           // grid = 16*64 = 1024 blocks = 4 blocks/CU = 4 waves/SIMD
#define CH 64           // j's per block
#define NPAIR (CH / 2)  // 32 packed j-pairs per block
#define KATAN 0.6366197723675814f   // 2/pi (folds 4/pi^2 into atan)
#define SQL2E 1.2011224087864498f   // sqrt(log2 e), folds exp->exp2 into conf
#define ISQL2E 0.8325546111576977f  // 1/SQL2E, unfolds cf2 in a0 (measured absmax 0)

typedef float v2f __attribute__((ext_vector_type(2)));

// d_ws: part[jt][c][i] : JT*6*N floats = 6.29 MB.
//
// r15 = r10 REVERT (77.75us, session best, absmax 0.0). Final structure.
//
// Session summary (15 rounds, all measured):
//   total 77.75 = harness poison-fill 41 (fixed, 53%) + main ~13 + epilogue
//   ~5 + 2 launch/gap slots ~8 + tails.
// Falsified directions: broadcast pipe relocation (r0 LDS=83.9, r1 VMEM=86.2,
// r2 readlane=95.9), row-amortization (r3=93.9 @ half-occupancy, r14
// ROWS=2 @ const-occupancy=79.7), prefetch+chain-shortening (r4=83.7),
// symmetry-halving (r5=95.1, bpermute overhead), 8 waves/SIMD (r6=91.2),
// inst-count halving via packed-v2f (r7=83.5 -- the loop was never
// issue-bound), single-dispatch fusion (r11 hung the container; r12
// hipLaunchCooperativeKernel silently no-ops under graph capture).
// Wins: r8 fusion+[c][i] layout (-2.2), r10 6-field LDS record + 4-thr/out
// epilogue (-3.5). r9 dispatch-twice probe measured main+gap = 21.7us.
//
// Kept techniques (absmax=0): packed-v2f one-rcp common-denominator CIoU:
//   P=(v+1+eps)*uni-inter (=den*uni, clamp>=1e-12; cancels in the ratio on
//   the diagonal), ciou=[P*(inter*c2-rho2*uni)-v^2*uni^2*c2]/(uni*c2*P);
// 6-field LDS record (3x ds_read_b128 broadcast/pair-iter), derived j-fields
// in VALU, a0 cf2-folded + ISQL2E unfold at store, eps split across records,
// 4/pi^2 folded into atan, log2(e) folded into conf for v_exp_f32.
// NO 2nd __launch_bounds__ arg (measured: forcing waves/EU spills ~90MB).

__device__ __forceinline__ v2f min2(v2f a, v2f b) {
    v2f r; r.x = fminf(a.x, b.x); r.y = fminf(a.y, b.y); return r;
}
__device__ __forceinline__ v2f max2(v2f a, v2f b) {
    v2f r; r.x = fmaxf(a.x, b.x); r.y = fmaxf(a.y, b.y); return r;
}
__device__ __forceinline__ v2f rcp2(v2f a) {
    v2f r; r.x = __builtin_amdgcn_rcpf(a.x); r.y = __builtin_amdgcn_rcpf(a.y); return r;
}
__device__ __forceinline__ v2f exp22(v2f a) {
    v2f r; r.x = __builtin_amdgcn_exp2f(a.x); r.y = __builtin_amdgcn_exp2f(a.y); return r;
}

// Packed-SoA pair records in LDS: pair p stride 12 floats (48 B, 16-aligned):
// [x1a,x1b, y1a,y1b, x2a,x2b, y2a,y2b, ata,atb, cf2a,cf2b]
__global__ __launch_bounds__(BLK) void ciou_attn_kernel(
        const float* __restrict__ x,
        float* __restrict__ part) {
    __shared__ float jrec[NPAIR * 12];   // 1.5 KB
    const int tid = threadIdx.x;
    const int gb = blockIdx.x / JT;
    const int jt = blockIdx.x % JT;
    const int i = gb * BLK + tid;

    // Stage j-chunk in-kernel (first CH threads; one atanf each).
    if (tid < CH) {
        int j = jt * CH + tid;
        float cf = x[j * 5 + 0], jx1 = x[j * 5 + 1], jy1 = x[j * 5 + 2];
        float jx2 = x[j * 5 + 3], jy2 = x[j * 5 + 4];
        float* dp = &jrec[(tid >> 1) * 12 + (tid & 1)];
        dp[0]  = jx1;  dp[2] = jy1;  dp[4] = jx2;  dp[6] = jy2;
        dp[8]  = KATAN * atanf((jx2 - jx1) / ((jy2 - jy1) + FEPS));
        dp[10] = cf * SQL2E;
    }

    // Per-lane row record.
    const float rx1 = x[i * 5 + 1], ry1 = x[i * 5 + 2];
    const float rx2 = x[i * 5 + 3], ry2 = x[i * 5 + 4];
    const float rw = rx2 - rx1, rh = ry2 - ry1;
    const float rhx = (rx1 + rx2) * 0.5f, rhy = (ry1 + ry2) * 0.5f;
    const float rareps = fmaf(rw, rh, HEPS);
    const float rat = KATAN * atanf(rw / (rh + FEPS));
    const float rcf2 = x[i * 5 + 0] * SQL2E;

    __syncthreads();

    v2f sum = 0.f, a0 = 0.f, a1 = 0.f, a2 = 0.f, a3 = 0.f, a4 = 0.f;
    const float ONEP = 1.f + FEPS;

#pragma unroll 4
    for (int p = 0; p < NPAIR; p++) {
        const float* f = &jrec[p * 12];   // uniform addr -> 3x b128 broadcast
        const v2f X1 = *(const v2f*)(f + 0),  Y1 = *(const v2f*)(f + 2);
        const v2f X2 = *(const v2f*)(f + 4),  Y2 = *(const v2f*)(f + 6);
        const v2f AT = *(const v2f*)(f + 8),  CF2 = *(const v2f*)(f + 10);
        // Derived j-fields in VALU (the non-bottleneck pipe).
        const v2f W = X2 - X1, H = Y2 - Y1;
        const v2f HX = (X1 + X2) * 0.5f, HY = (Y1 + Y2) * 0.5f;
        const v2f AR = W * H + HEPS;

        v2f iwr = min2(rx2, X2) - max2(rx1, X1);
        v2f ihr = min2(ry2, Y2) - max2(ry1, Y1);
        v2f inter = max2(iwr, 0.f) * max2(ihr, 0.f);
        v2f uni = (rareps + AR) - inter;
        v2f cw = (rw + W) - iwr;             // enclosing box identity
        v2f chh = (rh + H) - ihr;
        v2f c2 = cw * cw + chh * chh + FEPS;
        v2f dx = HX - rhx;
        v2f dy = HY - rhy;
        v2f rho2 = dx * dx + dy * dy;        // /4 pre-folded
        v2f da = AT - rat;                   // 4/pi^2 pre-folded
        v2f v = da * da;
        v2f P = (v + ONEP) * uni - inter;    // den*uni
        P = max2(P, 1e-12f);                 // fp-cancellation guard
        v2f rr = rcp2(uni * c2 * P);         // one rcp per pair
        v2f t1 = inter * c2 - rho2 * uni;
        v2f vu = v * uni;
        v2f num = t1 * P - (vu * vu) * c2;
        v2f e = exp22((num * rr) * (rcf2 * CF2));
        sum += e;
        a0 += e * CF2;                        // cf2-folded; unfold at store
        a1 += e * X1;
        a2 += e * Y1;
        a3 += e * X2;
        a4 += e * Y2;
    }

    // Coalesced partial stores: [jt][c][i], lanes contiguous in i.
    float* p = part + (size_t)jt * 6 * N;
    p[0 * N + i] = sum.x + sum.y;
    p[1 * N + i] = (a0.x + a0.y) * ISQL2E;
    p[2 * N + i] = a1.x + a1.y;
    p[3 * N + i] = a2.x + a2.y;
    p[4 * N + i] = a3.x + a3.y;
    p[5 * N + i] = a4.x + a4.y;
}

// 4 threads per output element: thread (o=t&63, q=t>>6) sums jt-slots
// [q*16, q*16+16); LDS reduce across q; t<64 finishes. 320 blocks = 1280
// waves -> load latency hidden. All part loads coalesced (block's 64
// outputs share c since 64 | N, i contiguous).
__global__ void epilogue_kernel(const float* __restrict__ x,
                                const float* __restrict__ gamma,
                                const float* __restrict__ part,
                                float* __restrict__ out) {
    __shared__ float red[2][BLK];
    const int t = threadIdx.x;
    const int o = t & 63, q = t >> 6;
    const int idx = blockIdx.x * 64 + o;
    const int c = idx / N, i = idx - c * N;
    float se = 0.f, a = 0.f;
    const float* ps = part + (size_t)(q * 16) * 6 * N;
#pragma unroll
    for (int k = 0; k < 16; k++) {
        const float* p = ps + (size_t)k * 6 * N;
        se += p[0 * N + i];
        a  += p[(1 + c) * N + i];
    }
    red[0][t] = se; red[1][t] = a;
    __syncthreads();
    if (t < 64) {
        float se4 = (red[0][t] + red[0][t + 64]) + (red[0][t + 128] + red[0][t + 192]);
        float a4  = (red[1][t] + red[1][t + 64]) + (red[1][t + 128] + red[1][t + 192]);
        float xp = x[i * 5 + c] * gamma[0] + a4 / se4;
        out[i * 5 + c] = 1.f / (1.f + expf(-xp));
    }
}

extern "C" void kernel_launch(void* const* d_in, const int* in_sizes, int n_in,
                              void* d_out, int out_size, void* d_ws, size_t ws_size,
                              hipStream_t stream) {
    const float* x = (const float*)d_in[0];
    const float* gamma = (const float*)d_in[1];
    float* out = (float*)d_out;
    float* part = (float*)d_ws;  // JT*6*N floats = 6.29 MB

    ciou_attn_kernel<<<(N / BLK) * JT, BLK, 0, stream>>>(x, part);
    epilogue_kernel<<<(N * 5) / 64, BLK, 0, stream>>>(x, gamma, part, out);
}